// Round 2
// baseline (634.396 us; speedup 1.0000x reference)
//
#include <hip/hip_runtime.h>
#include <math.h>

#define BB 2
#define CC 128
#define LL 4096
#define DIM 256
#define SS 16
#define RR 8
#define NLAYER 2
#define FFD 512
#define NCH 128
#define TC 32

__device__ __forceinline__ float sigmoidf_(float x){ return 1.0f/(1.0f + __expf(-x)); }
__device__ __forceinline__ float siluf_(float x){ return x * sigmoidf_(x); }
__device__ __forceinline__ float softplusf_(float x){ return fmaxf(x,0.0f) + log1pf(__expf(-fabsf(x))); }

// ---------------- LayerNorm over 128 features, 1 wave per row ----------------
__global__ void ln_kernel(const float* __restrict__ in, float* __restrict__ out,
                          const float* __restrict__ g, const float* __restrict__ b, int rows){
  int wave = threadIdx.x >> 6; int lane = threadIdx.x & 63;
  int row = blockIdx.x*4 + wave;
  if(row >= rows) return;
  const float* p = in + (size_t)row*CC;
  float x0 = p[lane], x1 = p[lane+64];
  float s = x0 + x1;
  #pragma unroll
  for(int o=32;o>0;o>>=1) s += __shfl_xor(s,o);
  float mean = s * (1.0f/128.0f);
  float d0 = x0-mean, d1 = x1-mean;
  float v = d0*d0 + d1*d1;
  #pragma unroll
  for(int o=32;o>0;o>>=1) v += __shfl_xor(v,o);
  float rs = rsqrtf(v*(1.0f/128.0f) + 1e-5f);
  float* q = out + (size_t)row*CC;
  q[lane]    = d0*rs*g[lane]    + b[lane];
  q[lane+64] = d1*rs*g[lane+64] + b[lane+64];
}

// ---------------- fp32 GEMM: C[n,j] = sum_k A[n,k]*W[j,k] (+bias[j]), epilogue ----
// EPI: 0 = none, 1 = exact gelu. AT: A is (B, K, Lt) channel-major (n = b*Lt + l).
template<int EPI, bool AT>
__global__ void gemm_kernel(const float* __restrict__ A, const float* __restrict__ W,
                            const float* __restrict__ bias, float* __restrict__ Co,
                            int N, int K, int J, int Lt){
  __shared__ float As[16][68];
  __shared__ float Ws[16][68];
  int tid = threadIdx.x;
  int tx = tid & 15, ty = tid >> 4;
  int n0 = blockIdx.x * 64, j0 = blockIdx.y * 64;
  float acc[4][4] = {};
  for(int kb=0; kb<K; kb+=16){
    if(AT){
      #pragma unroll
      for(int q=0;q<4;q++){
        int idx = tid + q*256;
        int kk = idx >> 6, r = idx & 63;
        int n = n0 + r; int bb = n / Lt; int l = n - bb*Lt;
        As[kk][r] = A[((size_t)(bb*K + kb+kk))*Lt + l];
      }
    } else {
      #pragma unroll
      for(int q=0;q<4;q++){
        int idx = tid + q*256;
        int r = idx >> 4, kk = idx & 15;
        As[kk][r] = A[(size_t)(n0 + r)*K + kb + kk];
      }
    }
    #pragma unroll
    for(int q=0;q<4;q++){
      int idx = tid + q*256;
      int c = idx >> 4, kk = idx & 15;
      int j = j0 + c;
      Ws[kk][c] = (j < J) ? W[(size_t)j*K + kb + kk] : 0.0f;
    }
    __syncthreads();
    #pragma unroll
    for(int kk=0;kk<16;kk++){
      float4 a = *(const float4*)&As[kk][ty*4];
      float4 w = *(const float4*)&Ws[kk][tx*4];
      float av[4] = {a.x,a.y,a.z,a.w};
      float wv[4] = {w.x,w.y,w.z,w.w};
      #pragma unroll
      for(int i2=0;i2<4;i2++)
        #pragma unroll
        for(int j2=0;j2<4;j2++)
          acc[i2][j2] = fmaf(av[i2], wv[j2], acc[i2][j2]);
    }
    __syncthreads();
  }
  #pragma unroll
  for(int i2=0;i2<4;i2++){
    int n = n0 + ty*4 + i2;
    #pragma unroll
    for(int j2=0;j2<4;j2++){
      int j = j0 + tx*4 + j2;
      if(j < J){
        float v = acc[i2][j2];
        if(bias) v += bias[j];
        if(EPI==1) v = 0.5f*v*(1.0f + erff(v*0.70710678118f));
        Co[(size_t)n*J + j] = v;
      }
    }
  }
}

// ---------------- causal depthwise conv (both directions) + silu --------------
__global__ void conv_kernel(const float* __restrict__ xz, const float* __restrict__ cw,
                            const float* __restrict__ cb, float* __restrict__ xc){
  int idx = blockIdx.x*256 + threadIdx.x; // (b,l,d), d fastest
  int d = idx & 255;
  int l = (idx >> 8) & 4095;
  int b = idx >> 20;
  const float* base = xz + (size_t)(b*LL)*512 + d;
  float w0 = cw[d*4+0], w1 = cw[d*4+1], w2 = cw[d*4+2], w3 = cw[d*4+3];
  float xm3 = (l>=3) ? base[(size_t)(l-3)*512] : 0.0f;
  float xm2 = (l>=2) ? base[(size_t)(l-2)*512] : 0.0f;
  float xm1 = (l>=1) ? base[(size_t)(l-1)*512] : 0.0f;
  float x0  = base[(size_t)l*512];
  float xp1 = (l<=LL-2) ? base[(size_t)(l+1)*512] : 0.0f;
  float xp2 = (l<=LL-3) ? base[(size_t)(l+2)*512] : 0.0f;
  float xp3 = (l<=LL-4) ? base[(size_t)(l+3)*512] : 0.0f;
  float bv = cb[d];
  float af = w0*xm3 + w1*xm2 + w2*xm1 + w3*x0 + bv;   // causal (fwd)
  float ab = w3*x0 + w2*xp1 + w1*xp2 + w0*xp3 + bv;   // anti-causal (bwd dir)
  size_t o = (size_t)(b*LL + l)*DIM + d;
  xc[o] = siluf_(af);
  xc[(size_t)BB*LL*DIM + o] = siluf_(ab);
}

// ---------------- dt = softplus(dbc[:, :8] @ dt_w^T + dt_b) -------------------
__global__ void dt_kernel(const float* __restrict__ dbc, const float* __restrict__ dtw,
                          const float* __restrict__ dtb, float* __restrict__ dt){
  int idx = blockIdx.x*256 + threadIdx.x;
  int dj = idx & 255;
  int row = idx >> 8;            // 0..16383 (dir,b,l)
  const float* p = dbc + (size_t)row*40;
  const float* w = dtw + dj*8;
  float acc = dtb[dj];
  #pragma unroll
  for(int r=0;r<8;r++) acc = fmaf(p[r], w[r], acc);
  dt[(size_t)row*DIM + dj] = softplusf_(acc);
}

// ---------------- scan phase A: per-chunk (a = exp(A*sum dt), acc) ------------
__global__ void scanA_kernel(const float* __restrict__ dt, const float* __restrict__ xc,
                             const float* __restrict__ dbc, const float* __restrict__ Alog,
                             float* __restrict__ aprod, float* __restrict__ bacc){
  int blk = blockIdx.x;          // (db*NCH + ch), db = dir*BB+b
  int ch = blk & (NCH-1);
  int db = blk >> 7;
  int dir = db >> 1;
  int d = threadIdx.x;
  __shared__ float Bs[TC][SS];
  size_t rowbase = (size_t)db * LL;
  for(int idx = threadIdx.x; idx < TC*SS; idx += 256){
    int jj = idx >> 4, s = idx & 15;
    int j = ch*TC + jj;
    int l = dir ? (LL-1-j) : j;
    Bs[jj][s] = dbc[(rowbase + l)*40 + 8 + s];
  }
  __syncthreads();
  float Av[SS];
  #pragma unroll
  for(int s=0;s<SS;s++) Av[s] = -__expf(Alog[d*SS+s]);
  float acc[SS];
  #pragma unroll
  for(int s=0;s<SS;s++) acc[s]=0.0f;
  float dts = 0.0f;
  for(int jj=0;jj<TC;jj++){
    int j = ch*TC + jj;
    int l = dir ? (LL-1-j) : j;
    float dtv = dt[(rowbase + l)*DIM + d];
    float xcv = xc[(rowbase + l)*DIM + d];
    float dx = dtv * xcv;
    dts += dtv;
    #pragma unroll
    for(int s=0;s<SS;s++){
      float e = __expf(dtv * Av[s]);
      acc[s] = fmaf(e, acc[s], dx * Bs[jj][s]);
    }
  }
  size_t obase = (size_t)blk*SS*DIM + d;
  #pragma unroll
  for(int s=0;s<SS;s++){
    aprod[obase + s*DIM] = __expf(dts * Av[s]);
    bacc[obase + s*DIM]  = acc[s];
  }
}

// ---------------- scan phase B: inter-chunk prefix ---------------------------
__global__ void scanB_kernel(const float* __restrict__ aprod, const float* __restrict__ bacc,
                             float* __restrict__ hinit){
  int idx = blockIdx.x*256 + threadIdx.x; // (db, s, d)
  int d = idx & 255;
  int s = (idx >> 8) & 15;
  int db = idx >> 12;
  float carry = 0.0f;
  for(int ch=0; ch<NCH; ch++){
    size_t o = ((size_t)(db*NCH + ch)*SS + s)*DIM + d;
    hinit[o] = carry;
    carry = fmaf(aprod[o], carry, bacc[o]);
  }
}

// ---------------- scan phase C: recompute with init, y = (sum hC + Dp*xc)*silu(z)
__global__ void scanC_kernel(const float* __restrict__ dt, const float* __restrict__ xc,
                             const float* __restrict__ dbc, const float* __restrict__ xz,
                             const float* __restrict__ Alog, const float* __restrict__ Dp,
                             const float* __restrict__ hinit, float* __restrict__ y){
  int blk = blockIdx.x;
  int ch = blk & (NCH-1);
  int db = blk >> 7;
  int dir = db >> 1; int b = db & 1;
  int d = threadIdx.x;
  __shared__ float Bs[TC][SS];
  __shared__ float Cs[TC][SS];
  size_t rowbase = (size_t)db * LL;
  for(int idx = threadIdx.x; idx < TC*SS; idx += 256){
    int jj = idx >> 4, s = idx & 15;
    int j = ch*TC + jj;
    int l = dir ? (LL-1-j) : j;
    Bs[jj][s] = dbc[(rowbase + l)*40 + 8 + s];
    Cs[jj][s] = dbc[(rowbase + l)*40 + 24 + s];
  }
  __syncthreads();
  float Av[SS], h[SS];
  #pragma unroll
  for(int s=0;s<SS;s++) Av[s] = -__expf(Alog[d*SS+s]);
  size_t hb = (size_t)blk*SS*DIM + d;
  #pragma unroll
  for(int s=0;s<SS;s++) h[s] = hinit[hb + s*DIM];
  float Dpv = Dp[d];
  for(int jj=0;jj<TC;jj++){
    int j = ch*TC + jj;
    int l = dir ? (LL-1-j) : j;
    float dtv = dt[(rowbase + l)*DIM + d];
    float xcv = xc[(rowbase + l)*DIM + d];
    float zv = xz[((size_t)(b*LL + l))*512 + DIM + d];
    float dx = dtv * xcv;
    float yv = 0.0f;
    #pragma unroll
    for(int s=0;s<SS;s++){
      float e = __expf(dtv * Av[s]);
      h[s] = fmaf(e, h[s], dx * Bs[jj][s]);
      yv = fmaf(h[s], Cs[jj][s], yv);
    }
    yv = fmaf(Dpv, xcv, yv);
    y[(rowbase + l)*DIM + d] = yv * siluf_(zv);
  }
}

// ---------------- elementwise helpers ----------------------------------------
__global__ void copy_kernel(const float* __restrict__ src, float* __restrict__ dst){
  int t = blockIdx.x*256 + threadIdx.x;
  size_t o = (size_t)t*4;
  *(float4*)(dst + o) = *(const float4*)(src + o);
}

__global__ void addu_kernel(const float* __restrict__ xf, const float* __restrict__ m,
                            float* __restrict__ u){
  int t = blockIdx.x*256 + threadIdx.x;    // 262144 per dir
  int dir = blockIdx.y;
  size_t NB = (size_t)BB*LL*CC;
  size_t o = (size_t)t*4;
  float4 a = *(const float4*)(xf + o);
  float4 c = *(const float4*)(m + dir*NB + o);
  float4 r; r.x=a.x+c.x; r.y=a.y+c.y; r.z=a.z+c.z; r.w=a.w+c.w;
  *(float4*)(u + dir*NB + o) = r;
}

__global__ void comb_kernel(const float* __restrict__ u, const float* __restrict__ f2,
                            float* __restrict__ xf){
  int t = blockIdx.x*256 + threadIdx.x;    // 262144
  size_t NB = (size_t)BB*LL*CC;
  size_t o = (size_t)t*4;
  float4 u0 = *(const float4*)(u + o);
  float4 u1 = *(const float4*)(u + NB + o);
  float4 a0 = *(const float4*)(f2 + o);
  float4 a1 = *(const float4*)(f2 + NB + o);
  float4 r;
  r.x = u0.x+u1.x+a0.x+a1.x; r.y = u0.y+u1.y+a0.y+a1.y;
  r.z = u0.z+u1.z+a0.z+a1.z; r.w = u0.w+u1.w+a0.w+a1.w;
  *(float4*)(xf + o) = r;
}

__global__ void out_kernel(const float* __restrict__ x, const float* __restrict__ gt,
                           const float* __restrict__ enh, float* __restrict__ out){
  int idx = blockIdx.x*256 + threadIdx.x;  // (b,c,l), l fastest
  int l = idx & 4095;
  int c = (idx >> 12) & 127;
  int b = idx >> 19;
  size_t ro = ((size_t)(b*LL + l))*CC + c;
  float g = sigmoidf_(gt[ro]);
  float e = enh[ro];
  out[idx] = x[idx] + g*e;
}

// =============================================================================
extern "C" void kernel_launch(void* const* d_in, const int* in_sizes, int n_in,
                              void* d_out, int out_size, void* d_ws, size_t ws_size,
                              hipStream_t stream){
  (void)in_sizes; (void)n_in; (void)out_size; (void)ws_size;
  const float* x        = (const float*)d_in[0];
  const float* embed_w  = (const float*)d_in[1];
  const float* embed_b  = (const float*)d_in[2];
  const float* outp_w   = (const float*)d_in[3];
  const float* outp_b   = (const float*)d_in[4];
  const float* gate_w   = (const float*)d_in[5];
  const float* gate_b   = (const float*)d_in[6];
  const float* norm_g   = (const float*)d_in[7];
  const float* norm_b   = (const float*)d_in[8];
  const float* in_proj_w= (const float*)d_in[9];
  const float* conv_w   = (const float*)d_in[10];
  const float* conv_b   = (const float*)d_in[11];
  const float* x_proj_w = (const float*)d_in[12];
  const float* dt_w     = (const float*)d_in[13];
  const float* dt_b     = (const float*)d_in[14];
  const float* A_log    = (const float*)d_in[15];
  const float* Dp       = (const float*)d_in[16];
  const float* m_out_w  = (const float*)d_in[17];
  const float* ffn_w1   = (const float*)d_in[18];
  const float* ffn_b1   = (const float*)d_in[19];
  const float* ffn_w2   = (const float*)d_in[20];
  const float* ffn_b2   = (const float*)d_in[21];
  float* out = (float*)d_out;

  float* ws = (float*)d_ws;
  const size_t M1 = (size_t)BB*LL*CC;      // 1,048,576 elements
  float* xe    = ws;                        // 1M
  float* xf    = ws + 1*M1;                 // 1M
  float* hbuf  = ws + 2*M1;                 // 1M : h / dbc / enh
  float* xzbuf = ws + 3*M1;                 // 4M : xz / gt
  float* xcbuf = ws + 7*M1;                 // 4M
  float* dtbuf = ws + 11*M1;                // 4M
  float* ybuf  = ws + 15*M1;                // 4M
  float* mbuf  = ws + 19*M1;                // 2M : m / h2
  float* ubuf  = ws + 21*M1;                // 2M
  float* f2buf = ws + 23*M1;                // 2M
  float* ap    = ws + 25*M1;                // 2M scan temp
  float* bacc  = ws + 27*M1;                // 2M scan temp
  float* hi    = ws + 29*M1;                // 2M scan temp
  float* ffnh  = ws + 25*M1;                // 8M (reuses scan temps after they are dead)

  const int N1 = BB*LL;          // 8192 rows
  const int N2 = 2*BB*LL;        // 16384 rows (dir-batched)

  // embed: xe = x^T @ embed_w^T + embed_b  (A transposed from BCHW)
  gemm_kernel<0,true><<<dim3(N1/64, 2), 256, 0, stream>>>(x, embed_w, embed_b, xe, N1, CC, CC, LL);
  copy_kernel<<<1024, 256, 0, stream>>>(xe, xf);

  for(int i=0;i<NLAYER;i++){
    const float* ng = norm_g + i*CC;
    const float* nb = norm_b + i*CC;
    // LN1 (shared between directions)
    ln_kernel<<<N1/4, 256, 0, stream>>>(xf, hbuf, ng, nb, N1);
    // xz = h @ in_proj^T  (8192 x 512)
    gemm_kernel<0,false><<<dim3(N1/64, 8), 256, 0, stream>>>(hbuf, in_proj_w + (size_t)i*2*DIM*CC, nullptr, xzbuf, N1, CC, 2*DIM, 0);
    // conv + silu, both directions
    conv_kernel<<<(BB*LL*DIM)/256, 256, 0, stream>>>(xzbuf, conv_w + i*DIM*4, conv_b + i*DIM, xcbuf);
    // dbc = xc @ x_proj^T (16384 x 40)
    gemm_kernel<0,false><<<dim3(N2/64, 1), 256, 0, stream>>>(xcbuf, x_proj_w + (size_t)i*40*DIM, nullptr, hbuf, N2, DIM, 40, 0);
    // dt
    dt_kernel<<<(N2*DIM)/256, 256, 0, stream>>>(hbuf, dt_w + (size_t)i*DIM*RR, dt_b + i*DIM, dtbuf);
    // chunked scan
    scanA_kernel<<<2*BB*NCH, 256, 0, stream>>>(dtbuf, xcbuf, hbuf, A_log + (size_t)i*DIM*SS, ap, bacc);
    scanB_kernel<<<(2*BB*SS*DIM)/256, 256, 0, stream>>>(ap, bacc, hi);
    scanC_kernel<<<2*BB*NCH, 256, 0, stream>>>(dtbuf, xcbuf, hbuf, xzbuf, A_log + (size_t)i*DIM*SS, Dp + i*DIM, hi, ybuf);
    // m = y @ mamba_out^T (16384 x 128)
    gemm_kernel<0,false><<<dim3(N2/64, 2), 256, 0, stream>>>(ybuf, m_out_w + (size_t)i*CC*DIM, nullptr, mbuf, N2, DIM, CC, 0);
    // u = xf + m
    addu_kernel<<<dim3(M1/1024, 2), 256, 0, stream>>>(xf, mbuf, ubuf);
    // LN2 on both dirs
    ln_kernel<<<N2/4, 256, 0, stream>>>(ubuf, mbuf, ng, nb, N2);
    // ffn1 + gelu (16384 x 512)
    gemm_kernel<1,false><<<dim3(N2/64, 8), 256, 0, stream>>>(mbuf, ffn_w1 + (size_t)i*FFD*CC, ffn_b1 + i*FFD, ffnh, N2, CC, FFD, 0);
    // ffn2 (16384 x 128)
    gemm_kernel<0,false><<<dim3(N2/64, 2), 256, 0, stream>>>(ffnh, ffn_w2 + (size_t)i*CC*FFD, ffn_b2 + i*CC, f2buf, N2, FFD, CC, 0);
    // xf = (u_f + f2_f) + (u_b + f2_b)
    comb_kernel<<<M1/1024, 256, 0, stream>>>(ubuf, f2buf, xf);
  }

  // enh = xf @ outp^T + outp_b ; gt = xe @ gate^T + gate_b
  gemm_kernel<0,false><<<dim3(N1/64, 2), 256, 0, stream>>>(xf, outp_w, outp_b, hbuf, N1, CC, CC, 0);
  gemm_kernel<0,false><<<dim3(N1/64, 2), 256, 0, stream>>>(xe, gate_w, gate_b, xzbuf, N1, CC, CC, 0);
  // out = x + sigmoid(gt) * enh  (transpose back to BCHW)
  out_kernel<<<(BB*CC*LL)/256, 256, 0, stream>>>(x, xzbuf, hbuf, out);
}

// Round 4
// 395.332 us; speedup vs baseline: 1.6047x; 1.6047x over previous
//
#include <hip/hip_runtime.h>
#include <math.h>

#define BB 2
#define CC 128
#define LL 4096
#define DIM 256
#define SS 16
#define RR 8
#define NLAYER 2
#define FFD 512
#define NCH 128
#define TC 32

typedef unsigned short u16;
typedef unsigned int u32;
typedef __bf16 bf16x8 __attribute__((ext_vector_type(8)));
typedef float f32x4 __attribute__((ext_vector_type(4)));
typedef u16 u16x4 __attribute__((ext_vector_type(4)));

__device__ __forceinline__ float sigmoidf_(float x){ return 1.0f/(1.0f + __expf(-x)); }
__device__ __forceinline__ float siluf_(float x){ return x * sigmoidf_(x); }
__device__ __forceinline__ float softplusf_(float x){ return fmaxf(x,0.0f) + log1pf(__expf(-fabsf(x))); }
__device__ __forceinline__ u16 f2bf(float f){
  union { float f; u32 u; } v; v.f = f;
  u32 r = v.u + 0x7FFFu + ((v.u >> 16) & 1u);
  return (u16)(r >> 16);
}

// ---------------- LayerNorm over 128 features, 1 wave per row ----------------
__global__ void ln_kernel(const float* __restrict__ in, float* __restrict__ out,
                          const float* __restrict__ g, const float* __restrict__ b, int rows){
  int wave = threadIdx.x >> 6; int lane = threadIdx.x & 63;
  int row = blockIdx.x*4 + wave;
  if(row >= rows) return;
  const float* p = in + (size_t)row*CC;
  float x0 = p[lane], x1 = p[lane+64];
  float s = x0 + x1;
  #pragma unroll
  for(int o=32;o>0;o>>=1) s += __shfl_xor(s,o);
  float mean = s * (1.0f/128.0f);
  float d0 = x0-mean, d1 = x1-mean;
  float v = d0*d0 + d1*d1;
  #pragma unroll
  for(int o=32;o>0;o>>=1) v += __shfl_xor(v,o);
  float rs = rsqrtf(v*(1.0f/128.0f) + 1e-5f);
  float* q = out + (size_t)row*CC;
  q[lane]    = d0*rs*g[lane]    + b[lane];
  q[lane+64] = d1*rs*g[lane+64] + b[lane+64];
}

// ---------------- bf16 MFMA GEMM: C[n,j] = sum_k A[n,k]*W[j,k] (+bias), epilogue
// EPI: 0 = none, 1 = exact gelu. AT: A is (B, K, Lt) channel-major (n = b*Lt + l).
// Block tile 64x64, 4 waves (2x2), wave tile 32x32 via 2x2 MFMA 16x16x32 frags.
#define LDP 40   // LDS row stride in u16 (32 + 8 pad = 80B)
template<int EPI, bool AT>
__global__ void mgemm_kernel(const float* __restrict__ A, const float* __restrict__ W,
                             const float* __restrict__ bias, float* __restrict__ Co,
                             int N, int K, int J, int Lt){
  __shared__ u16 As[64*LDP];
  __shared__ u16 Ws[64*LDP];
  int tid = threadIdx.x;
  int n0 = blockIdx.x * 64, j0 = blockIdx.y * 64;
  int w = tid >> 6, lane = tid & 63;
  int wm = w >> 1, wn = w & 1;
  int lr = lane & 15, lg = lane >> 4;
  f32x4 acc00 = {0.f,0.f,0.f,0.f}, acc01 = acc00, acc10 = acc00, acc11 = acc00;

  for(int kb = 0; kb < K; kb += 32){
    // ---- stage A tile (64 rows x 32 k) as bf16 ----
    if(AT){
      #pragma unroll
      for(int p=0;p<8;p++){
        int i = tid + p*256;         // 2048 elements
        int k = i >> 6, col = i & 63;
        int n = n0 + col; int bb = n / Lt; int l = n - bb*Lt;
        float v = A[((size_t)(bb*K + kb + k))*Lt + l];
        As[col*LDP + k] = f2bf(v);
      }
    } else {
      #pragma unroll
      for(int p=0;p<2;p++){
        int i = tid + p*256;         // 512 groups of 4 floats
        int row = i >> 3, cg = i & 7;
        float4 v = *(const float4*)&A[(size_t)(n0 + row)*K + kb + cg*4];
        u16x4 pk = { f2bf(v.x), f2bf(v.y), f2bf(v.z), f2bf(v.w) };
        *(u16x4*)&As[row*LDP + cg*4] = pk;
      }
    }
    // ---- stage W tile (64 j-rows x 32 k) ----
    #pragma unroll
    for(int p=0;p<2;p++){
      int i = tid + p*256;
      int row = i >> 3, cg = i & 7;
      int j = j0 + row;
      u16x4 pk;
      if(j < J){
        float4 v = *(const float4*)&W[(size_t)j*K + kb + cg*4];
        pk.x = f2bf(v.x); pk.y = f2bf(v.y); pk.z = f2bf(v.z); pk.w = f2bf(v.w);
      } else { pk.x = 0; pk.y = 0; pk.z = 0; pk.w = 0; }
      *(u16x4*)&Ws[row*LDP + cg*4] = pk;
    }
    __syncthreads();
    // ---- MFMA: A-frag row = lane&15, k = (lane>>4)*8 + e (contiguous 8) ----
    bf16x8 a0 = *(const bf16x8*)&As[(wm*32 +      lr)*LDP + lg*8];
    bf16x8 a1 = *(const bf16x8*)&As[(wm*32 + 16 + lr)*LDP + lg*8];
    bf16x8 b0 = *(const bf16x8*)&Ws[(wn*32 +      lr)*LDP + lg*8];
    bf16x8 b1 = *(const bf16x8*)&Ws[(wn*32 + 16 + lr)*LDP + lg*8];
    acc00 = __builtin_amdgcn_mfma_f32_16x16x32_bf16(a0, b0, acc00, 0, 0, 0);
    acc01 = __builtin_amdgcn_mfma_f32_16x16x32_bf16(a0, b1, acc01, 0, 0, 0);
    acc10 = __builtin_amdgcn_mfma_f32_16x16x32_bf16(a1, b0, acc10, 0, 0, 0);
    acc11 = __builtin_amdgcn_mfma_f32_16x16x32_bf16(a1, b1, acc11, 0, 0, 0);
    __syncthreads();
  }
  // ---- epilogue: D col = lane&15, row = (lane>>4)*4 + reg ----
  #pragma unroll
  for(int mi=0; mi<2; mi++){
    #pragma unroll
    for(int ni=0; ni<2; ni++){
      f32x4 a = (mi==0) ? (ni==0 ? acc00 : acc01) : (ni==0 ? acc10 : acc11);
      int j = j0 + wn*32 + ni*16 + lr;
      if(j < J){
        float bv = bias ? bias[j] : 0.0f;
        #pragma unroll
        for(int r=0;r<4;r++){
          int m = n0 + wm*32 + mi*16 + lg*4 + r;
          float v = a[r] + bv;
          if(EPI==1) v = 0.5f*v*(1.0f + erff(v*0.70710678118f));
          Co[(size_t)m*J + j] = v;
        }
      }
    }
  }
}

// ---------------- causal depthwise conv (both directions) + silu --------------
__global__ void conv_kernel(const float* __restrict__ xz, const float* __restrict__ cw,
                            const float* __restrict__ cb, float* __restrict__ xc){
  int idx = blockIdx.x*256 + threadIdx.x; // (b,l,d), d fastest
  int d = idx & 255;
  int l = (idx >> 8) & 4095;
  int b = idx >> 20;
  const float* base = xz + (size_t)(b*LL)*512 + d;
  float w0 = cw[d*4+0], w1 = cw[d*4+1], w2 = cw[d*4+2], w3 = cw[d*4+3];
  float xm3 = (l>=3) ? base[(size_t)(l-3)*512] : 0.0f;
  float xm2 = (l>=2) ? base[(size_t)(l-2)*512] : 0.0f;
  float xm1 = (l>=1) ? base[(size_t)(l-1)*512] : 0.0f;
  float x0  = base[(size_t)l*512];
  float xp1 = (l<=LL-2) ? base[(size_t)(l+1)*512] : 0.0f;
  float xp2 = (l<=LL-3) ? base[(size_t)(l+2)*512] : 0.0f;
  float xp3 = (l<=LL-4) ? base[(size_t)(l+3)*512] : 0.0f;
  float bv = cb[d];
  float af = w0*xm3 + w1*xm2 + w2*xm1 + w3*x0 + bv;   // causal (fwd)
  float ab = w3*x0 + w2*xp1 + w1*xp2 + w0*xp3 + bv;   // anti-causal (bwd dir)
  size_t o = (size_t)(b*LL + l)*DIM + d;
  xc[o] = siluf_(af);
  xc[(size_t)BB*LL*DIM + o] = siluf_(ab);
}

// ---------------- dt = softplus(dbc[:, :8] @ dt_w^T + dt_b) -------------------
__global__ void dt_kernel(const float* __restrict__ dbc, const float* __restrict__ dtw,
                          const float* __restrict__ dtb, float* __restrict__ dt){
  int idx = blockIdx.x*256 + threadIdx.x;
  int dj = idx & 255;
  int row = idx >> 8;            // 0..16383 (dir,b,l)
  const float* p = dbc + (size_t)row*40;
  const float* w = dtw + dj*8;
  float acc = dtb[dj];
  #pragma unroll
  for(int r=0;r<8;r++) acc = fmaf(p[r], w[r], acc);
  dt[(size_t)row*DIM + dj] = softplusf_(acc);
}

// ---------------- scan phase A: per-chunk (a = exp(A*sum dt), acc) ------------
__global__ void scanA_kernel(const float* __restrict__ dt, const float* __restrict__ xc,
                             const float* __restrict__ dbc, const float* __restrict__ Alog,
                             float* __restrict__ aprod, float* __restrict__ bacc){
  int blk = blockIdx.x;          // (db*NCH + ch), db = dir*BB+b
  int ch = blk & (NCH-1);
  int db = blk >> 7;
  int dir = db >> 1;
  int d = threadIdx.x;
  __shared__ float Bs[TC][SS];
  size_t rowbase = (size_t)db * LL;
  for(int idx = threadIdx.x; idx < TC*SS; idx += 256){
    int jj = idx >> 4, s = idx & 15;
    int j = ch*TC + jj;
    int l = dir ? (LL-1-j) : j;
    Bs[jj][s] = dbc[(rowbase + l)*40 + 8 + s];
  }
  __syncthreads();
  float Av[SS];
  #pragma unroll
  for(int s=0;s<SS;s++) Av[s] = -__expf(Alog[d*SS+s]);
  float acc[SS];
  #pragma unroll
  for(int s=0;s<SS;s++) acc[s]=0.0f;
  float dts = 0.0f;
  for(int jj=0;jj<TC;jj++){
    int j = ch*TC + jj;
    int l = dir ? (LL-1-j) : j;
    float dtv = dt[(rowbase + l)*DIM + d];
    float xcv = xc[(rowbase + l)*DIM + d];
    float dx = dtv * xcv;
    dts += dtv;
    #pragma unroll
    for(int s=0;s<SS;s++){
      float e = __expf(dtv * Av[s]);
      acc[s] = fmaf(e, acc[s], dx * Bs[jj][s]);
    }
  }
  size_t obase = (size_t)blk*SS*DIM + d;
  #pragma unroll
  for(int s=0;s<SS;s++){
    aprod[obase + s*DIM] = __expf(dts * Av[s]);
    bacc[obase + s*DIM]  = acc[s];
  }
}

// ---------------- scan phase B: inter-chunk prefix ---------------------------
__global__ void scanB_kernel(const float* __restrict__ aprod, const float* __restrict__ bacc,
                             float* __restrict__ hinit){
  int idx = blockIdx.x*256 + threadIdx.x; // (db, s, d)
  int d = idx & 255;
  int s = (idx >> 8) & 15;
  int db = idx >> 12;
  float carry = 0.0f;
  for(int ch=0; ch<NCH; ch++){
    size_t o = ((size_t)(db*NCH + ch)*SS + s)*DIM + d;
    hinit[o] = carry;
    carry = fmaf(aprod[o], carry, bacc[o]);
  }
}

// ---------------- scan phase C: recompute with init, y = (sum hC + Dp*xc)*silu(z)
__global__ void scanC_kernel(const float* __restrict__ dt, const float* __restrict__ xc,
                             const float* __restrict__ dbc, const float* __restrict__ xz,
                             const float* __restrict__ Alog, const float* __restrict__ Dp,
                             const float* __restrict__ hinit, float* __restrict__ y){
  int blk = blockIdx.x;
  int ch = blk & (NCH-1);
  int db = blk >> 7;
  int dir = db >> 1; int b = db & 1;
  int d = threadIdx.x;
  __shared__ float Bs[TC][SS];
  __shared__ float Cs[TC][SS];
  size_t rowbase = (size_t)db * LL;
  for(int idx = threadIdx.x; idx < TC*SS; idx += 256){
    int jj = idx >> 4, s = idx & 15;
    int j = ch*TC + jj;
    int l = dir ? (LL-1-j) : j;
    Bs[jj][s] = dbc[(rowbase + l)*40 + 8 + s];
    Cs[jj][s] = dbc[(rowbase + l)*40 + 24 + s];
  }
  __syncthreads();
  float Av[SS], h[SS];
  #pragma unroll
  for(int s=0;s<SS;s++) Av[s] = -__expf(Alog[d*SS+s]);
  size_t hb = (size_t)blk*SS*DIM + d;
  #pragma unroll
  for(int s=0;s<SS;s++) h[s] = hinit[hb + s*DIM];
  float Dpv = Dp[d];
  for(int jj=0;jj<TC;jj++){
    int j = ch*TC + jj;
    int l = dir ? (LL-1-j) : j;
    float dtv = dt[(rowbase + l)*DIM + d];
    float xcv = xc[(rowbase + l)*DIM + d];
    float zv = xz[((size_t)(b*LL + l))*512 + DIM + d];
    float dx = dtv * xcv;
    float yv = 0.0f;
    #pragma unroll
    for(int s=0;s<SS;s++){
      float e = __expf(dtv * Av[s]);
      h[s] = fmaf(e, h[s], dx * Bs[jj][s]);
      yv = fmaf(h[s], Cs[jj][s], yv);
    }
    yv = fmaf(Dpv, xcv, yv);
    y[(rowbase + l)*DIM + d] = yv * siluf_(zv);
  }
}

// ---------------- elementwise helpers ----------------------------------------
__global__ void copy_kernel(const float* __restrict__ src, float* __restrict__ dst){
  int t = blockIdx.x*256 + threadIdx.x;
  size_t o = (size_t)t*4;
  *(float4*)(dst + o) = *(const float4*)(src + o);
}

__global__ void addu_kernel(const float* __restrict__ xf, const float* __restrict__ m,
                            float* __restrict__ u){
  int t = blockIdx.x*256 + threadIdx.x;    // 262144 per dir
  int dir = blockIdx.y;
  size_t NB = (size_t)BB*LL*CC;
  size_t o = (size_t)t*4;
  float4 a = *(const float4*)(xf + o);
  float4 c = *(const float4*)(m + dir*NB + o);
  float4 r; r.x=a.x+c.x; r.y=a.y+c.y; r.z=a.z+c.z; r.w=a.w+c.w;
  *(float4*)(u + dir*NB + o) = r;
}

__global__ void comb_kernel(const float* __restrict__ u, const float* __restrict__ f2,
                            float* __restrict__ xf){
  int t = blockIdx.x*256 + threadIdx.x;    // 262144
  size_t NB = (size_t)BB*LL*CC;
  size_t o = (size_t)t*4;
  float4 u0 = *(const float4*)(u + o);
  float4 u1 = *(const float4*)(u + NB + o);
  float4 a0 = *(const float4*)(f2 + o);
  float4 a1 = *(const float4*)(f2 + NB + o);
  float4 r;
  r.x = u0.x+u1.x+a0.x+a1.x; r.y = u0.y+u1.y+a0.y+a1.y;
  r.z = u0.z+u1.z+a0.z+a1.z; r.w = u0.w+u1.w+a0.w+a1.w;
  *(float4*)(xf + o) = r;
}

__global__ void out_kernel(const float* __restrict__ x, const float* __restrict__ gt,
                           const float* __restrict__ enh, float* __restrict__ out){
  int idx = blockIdx.x*256 + threadIdx.x;  // (b,c,l), l fastest
  int l = idx & 4095;
  int c = (idx >> 12) & 127;
  int b = idx >> 19;
  size_t ro = ((size_t)(b*LL + l))*CC + c;
  float g = sigmoidf_(gt[ro]);
  float e = enh[ro];
  out[idx] = x[idx] + g*e;
}

// =============================================================================
extern "C" void kernel_launch(void* const* d_in, const int* in_sizes, int n_in,
                              void* d_out, int out_size, void* d_ws, size_t ws_size,
                              hipStream_t stream){
  (void)in_sizes; (void)n_in; (void)out_size; (void)ws_size;
  const float* x        = (const float*)d_in[0];
  const float* embed_w  = (const float*)d_in[1];
  const float* embed_b  = (const float*)d_in[2];
  const float* outp_w   = (const float*)d_in[3];
  const float* outp_b   = (const float*)d_in[4];
  const float* gate_w   = (const float*)d_in[5];
  const float* gate_b   = (const float*)d_in[6];
  const float* norm_g   = (const float*)d_in[7];
  const float* norm_b   = (const float*)d_in[8];
  const float* in_proj_w= (const float*)d_in[9];
  const float* conv_w   = (const float*)d_in[10];
  const float* conv_b   = (const float*)d_in[11];
  const float* x_proj_w = (const float*)d_in[12];
  const float* dt_w     = (const float*)d_in[13];
  const float* dt_b     = (const float*)d_in[14];
  const float* A_log    = (const float*)d_in[15];
  const float* Dp       = (const float*)d_in[16];
  const float* m_out_w  = (const float*)d_in[17];
  const float* ffn_w1   = (const float*)d_in[18];
  const float* ffn_b1   = (const float*)d_in[19];
  const float* ffn_w2   = (const float*)d_in[20];
  const float* ffn_b2   = (const float*)d_in[21];
  float* out = (float*)d_out;

  float* ws = (float*)d_ws;
  const size_t M1 = (size_t)BB*LL*CC;      // 1,048,576 elements
  float* xe    = ws;                        // 1M
  float* xf    = ws + 1*M1;                 // 1M
  float* hbuf  = ws + 2*M1;                 // 1M : h / dbc / enh
  float* xzbuf = ws + 3*M1;                 // 4M : xz / gt
  float* xcbuf = ws + 7*M1;                 // 4M
  float* dtbuf = ws + 11*M1;                // 4M
  float* ybuf  = ws + 15*M1;                // 4M
  float* mbuf  = ws + 19*M1;                // 2M : m / h2
  float* ubuf  = ws + 21*M1;                // 2M
  float* f2buf = ws + 23*M1;                // 2M
  float* ap    = ws + 25*M1;                // 2M scan temp
  float* bacc  = ws + 27*M1;                // 2M scan temp
  float* hi    = ws + 29*M1;                // 2M scan temp
  float* ffnh  = ws + 25*M1;                // 8M (reuses scan temps after they are dead)

  const int N1 = BB*LL;          // 8192 rows
  const int N2 = 2*BB*LL;        // 16384 rows (dir-batched)

  // embed: xe = x^T @ embed_w^T + embed_b  (A transposed from BCHW)
  mgemm_kernel<0,true><<<dim3(N1/64, 2), 256, 0, stream>>>(x, embed_w, embed_b, xe, N1, CC, CC, LL);
  copy_kernel<<<1024, 256, 0, stream>>>(xe, xf);

  for(int i=0;i<NLAYER;i++){
    const float* ng = norm_g + i*CC;
    const float* nb = norm_b + i*CC;
    // LN1 (shared between directions)
    ln_kernel<<<N1/4, 256, 0, stream>>>(xf, hbuf, ng, nb, N1);
    // xz = h @ in_proj^T  (8192 x 512)
    mgemm_kernel<0,false><<<dim3(N1/64, 8), 256, 0, stream>>>(hbuf, in_proj_w + (size_t)i*2*DIM*CC, nullptr, xzbuf, N1, CC, 2*DIM, 0);
    // conv + silu, both directions
    conv_kernel<<<(BB*LL*DIM)/256, 256, 0, stream>>>(xzbuf, conv_w + i*DIM*4, conv_b + i*DIM, xcbuf);
    // dbc = xc @ x_proj^T (16384 x 40)
    mgemm_kernel<0,false><<<dim3(N2/64, 1), 256, 0, stream>>>(xcbuf, x_proj_w + (size_t)i*40*DIM, nullptr, hbuf, N2, DIM, 40, 0);
    // dt
    dt_kernel<<<(N2*DIM)/256, 256, 0, stream>>>(hbuf, dt_w + (size_t)i*DIM*RR, dt_b + i*DIM, dtbuf);
    // chunked scan
    scanA_kernel<<<2*BB*NCH, 256, 0, stream>>>(dtbuf, xcbuf, hbuf, A_log + (size_t)i*DIM*SS, ap, bacc);
    scanB_kernel<<<(2*BB*SS*DIM)/256, 256, 0, stream>>>(ap, bacc, hi);
    scanC_kernel<<<2*BB*NCH, 256, 0, stream>>>(dtbuf, xcbuf, hbuf, xzbuf, A_log + (size_t)i*DIM*SS, Dp + i*DIM, hi, ybuf);
    // m = y @ mamba_out^T (16384 x 128)
    mgemm_kernel<0,false><<<dim3(N2/64, 2), 256, 0, stream>>>(ybuf, m_out_w + (size_t)i*CC*DIM, nullptr, mbuf, N2, DIM, CC, 0);
    // u = xf + m
    addu_kernel<<<dim3(M1/1024, 2), 256, 0, stream>>>(xf, mbuf, ubuf);
    // LN2 on both dirs
    ln_kernel<<<N2/4, 256, 0, stream>>>(ubuf, mbuf, ng, nb, N2);
    // ffn1 + gelu (16384 x 512)
    mgemm_kernel<1,false><<<dim3(N2/64, 8), 256, 0, stream>>>(mbuf, ffn_w1 + (size_t)i*FFD*CC, ffn_b1 + i*FFD, ffnh, N2, CC, FFD, 0);
    // ffn2 (16384 x 128)
    mgemm_kernel<0,false><<<dim3(N2/64, 2), 256, 0, stream>>>(ffnh, ffn_w2 + (size_t)i*CC*FFD, ffn_b2 + i*CC, f2buf, N2, FFD, CC, 0);
    // xf = (u_f + f2_f) + (u_b + f2_b)
    comb_kernel<<<M1/1024, 256, 0, stream>>>(ubuf, f2buf, xf);
  }

  // enh = xf @ outp^T + outp_b ; gt = xe @ gate^T + gate_b
  mgemm_kernel<0,false><<<dim3(N1/64, 2), 256, 0, stream>>>(xf, outp_w, outp_b, hbuf, N1, CC, CC, 0);
  mgemm_kernel<0,false><<<dim3(N1/64, 2), 256, 0, stream>>>(xe, gate_w, gate_b, xzbuf, N1, CC, CC, 0);
  // out = x + sigmoid(gt) * enh  (transpose back to BCHW)
  out_kernel<<<(BB*CC*LL)/256, 256, 0, stream>>>(x, xzbuf, hbuf, out);
}